// Round 1
// baseline (521.751 us; speedup 1.0000x reference)
//
#include <hip/hip_runtime.h>
#include <hip/hip_bf16.h>
#include <stdint.h>

// Problem constants (DGRUCell: DIM=512, BATCH=32768)
#define DIM      512
#define TWO_D    1024
#define FIVE_D   2560
#define BATCH    32768
#define LN_EPS   1e-5f
#define GATE_B   0.0f

typedef _Float16 f16x8 __attribute__((ext_vector_type(8)));
typedef _Float16 f16x4 __attribute__((ext_vector_type(4)));
typedef float    f32x4 __attribute__((ext_vector_type(4)));

// ---------------------------------------------------------------------------
// async global->LDS, 16B per lane. LDS dest = wave-uniform base + lane*16.
// ---------------------------------------------------------------------------
__device__ __forceinline__ void async_copy16(const void* g, void* l) {
  __builtin_amdgcn_global_load_lds(
      (const __attribute__((address_space(1))) uint32_t*)g,
      (__attribute__((address_space(3))) uint32_t*)l,
      16, 0, 0);
}

// ---------------------------------------------------------------------------
// K0: fp32 -> fp16 weight conversion (vector of 4 per thread)
// ---------------------------------------------------------------------------
__global__ __launch_bounds__(256)
void cvt_kernel(const float* __restrict__ s, _Float16* __restrict__ d, int n4) {
  int i = blockIdx.x * blockDim.x + threadIdx.x;
  if (i < n4) {
    float4 v = *(const float4*)(s + (size_t)i * 4);
    f16x4 o;
    o[0] = (_Float16)v.x; o[1] = (_Float16)v.y;
    o[2] = (_Float16)v.z; o[3] = (_Float16)v.w;
    *(f16x4*)&d[(size_t)i * 4] = o;
  }
}

// ---------------------------------------------------------------------------
// K1: LN1 over concat(x,h) -> inp fp16 [B, 1024]
// one row per block, 256 threads, 4 elems/thread
// ---------------------------------------------------------------------------
__global__ __launch_bounds__(256)
void ln1_kernel(const float* __restrict__ x, const float* __restrict__ h,
                const float* __restrict__ w, const float* __restrict__ b,
                const float* __restrict__ mask, _Float16* __restrict__ inp)
{
  const int row = blockIdx.x;
  const int t   = threadIdx.x;
  const int col = t * 4;
  const float* src = (col < DIM) ? (x + (size_t)row * DIM + col)
                                 : (h + (size_t)row * DIM + (col - DIM));
  float4 v = *(const float4*)src;
  float s = v.x + v.y + v.z + v.w;
  float q = v.x * v.x + v.y * v.y + v.z * v.z + v.w * v.w;
#pragma unroll
  for (int o = 32; o > 0; o >>= 1) { s += __shfl_xor(s, o); q += __shfl_xor(q, o); }
  __shared__ float red[8];
  const int wid = t >> 6;
  if ((t & 63) == 0) { red[wid] = s; red[4 + wid] = q; }
  __syncthreads();
  s = red[0] + red[1] + red[2] + red[3];
  q = red[4] + red[5] + red[6] + red[7];
  const float mu   = s * (1.0f / TWO_D);
  const float rstd = rsqrtf(q * (1.0f / TWO_D) - mu * mu + LN_EPS);
  float vv[4] = { v.x, v.y, v.z, v.w };
  f16x4 o4;
#pragma unroll
  for (int i = 0; i < 4; ++i)
    o4[i] = (_Float16)(((vv[i] - mu) * rstd * w[col + i] + b[col + i]) * mask[col + i]);
  *(f16x4*)&inp[(size_t)row * TWO_D + col] = o4;
}

// ---------------------------------------------------------------------------
// K3: gate nonlinearities + LN2 -> inp2 fp16; z0/z1 written in-place into the
// gates buffer (positions of g2/g3, read-before-write within the same thread).
// one row per block, 128 threads, j = 4 cols/thread
// ---------------------------------------------------------------------------
__global__ __launch_bounds__(128)
void gate_ln2_kernel(const float* __restrict__ x, const float* __restrict__ h,
                     _Float16* __restrict__ gates,
                     const float* __restrict__ w2, const float* __restrict__ b2,
                     const float* __restrict__ mask, _Float16* __restrict__ inp2)
{
  const int row = blockIdx.x;
  const int t   = threadIdx.x;
  const int j   = t * 4;
  _Float16* g = gates + (size_t)row * FIVE_D;

  f16x4 g0 = *(const f16x4*)&g[j];
  f16x4 g1 = *(const f16x4*)&g[DIM + j];
  f16x4 g2 = *(const f16x4*)&g[2 * DIM + j];
  f16x4 g3 = *(const f16x4*)&g[3 * DIM + j];
  f16x4 g4 = *(const f16x4*)&g[4 * DIM + j];
  float4 xv = *(const float4*)(x + (size_t)row * DIM + j);
  float4 hv = *(const float4*)(h + (size_t)row * DIM + j);
  float xa[4] = { xv.x, xv.y, xv.z, xv.w };
  float ha[4] = { hv.x, hv.y, hv.z, hv.w };

  float xr[4], hr[4];
  f16x4 z0s, z1s;
  float s = 0.f, q = 0.f;
#pragma unroll
  for (int i = 0; i < 4; ++i) {
    float rx = 1.0f / (1.0f + expf(-(float)g0[i]));
    float rh = 1.0f / (1.0f + expf(-(float)g1[i]));
    xr[i] = xa[i] * rx;
    hr[i] = ha[i] * rh;
    float a = (float)g2[i], bb = (float)g3[i], c = (float)g4[i] - GATE_B;
    float m = fmaxf(fmaxf(a, bb), c);
    float e0 = expf(a - m), e1 = expf(bb - m), e2 = expf(c - m);
    float inv = 1.0f / (e0 + e1 + e2);
    z0s[i] = (_Float16)(e0 * inv);
    z1s[i] = (_Float16)(e1 * inv);
    s += xr[i] + hr[i];
    q += xr[i] * xr[i] + hr[i] * hr[i];
  }
  *(f16x4*)&g[2 * DIM + j] = z0s;
  *(f16x4*)&g[3 * DIM + j] = z1s;

#pragma unroll
  for (int o = 32; o > 0; o >>= 1) { s += __shfl_xor(s, o); q += __shfl_xor(q, o); }
  __shared__ float red[4];
  const int wid = t >> 6;
  if ((t & 63) == 0) { red[wid] = s; red[2 + wid] = q; }
  __syncthreads();
  s = red[0] + red[1];
  q = red[2] + red[3];
  const float mu   = s * (1.0f / TWO_D);
  const float rstd = rsqrtf(q * (1.0f / TWO_D) - mu * mu + LN_EPS);

  f16x4 oA, oB;
#pragma unroll
  for (int i = 0; i < 4; ++i) {
    oA[i] = (_Float16)(((xr[i] - mu) * rstd * w2[j + i] + b2[j + i]) * mask[j + i]);
    oB[i] = (_Float16)(((hr[i] - mu) * rstd * w2[DIM + j + i] + b2[DIM + j + i]) * mask[DIM + j + i]);
  }
  *(f16x4*)&inp2[(size_t)row * TWO_D + j]       = oA;
  *(f16x4*)&inp2[(size_t)row * TWO_D + DIM + j] = oB;
}

// ---------------------------------------------------------------------------
// GEMM: C = A[M,K] @ B[N,K]^T (+bias). 128x128 tile, BK=32, 4 waves (2x2),
// each wave 64x64 = 4x4 frags of 16x16, mfma_f32_16x16x32_f16.
// MODE 0: store fp16 gates.  MODE 1: u=tanh(.) then h_new epilogue to fp32.
// ---------------------------------------------------------------------------
template<int MODE>
__global__ __launch_bounds__(256)
void gemm_f16(const _Float16* __restrict__ A,
              const _Float16* __restrict__ Bw,
              const float* __restrict__ bias,
              void* __restrict__ outp,
              const float* __restrict__ X,
              const float* __restrict__ H,
              const _Float16* __restrict__ G,
              int M, int N, int K, int nbx, int total)
{
  __shared__ _Float16 As[128 * 32];
  __shared__ _Float16 Bs[128 * 32];

  // XCD-aware swizzle (total % 8 == 0): each XCD gets a contiguous chunk so
  // consecutive blocks on one XCD share the A row-panel (L2 reuse).
  const int lbid  = blockIdx.x + gridDim.x * blockIdx.y;
  const int chunk = total >> 3;
  const int swz   = (lbid & 7) * chunk + (lbid >> 3);
  const int bxi   = swz % nbx;
  const int byi   = swz / nbx;
  const int brow  = byi * 128;
  const int bcol  = bxi * 128;

  const int tid  = threadIdx.x;
  const int lane = tid & 63;
  const int wid  = tid >> 6;    // 0..3
  const int wr   = wid >> 1;    // wave row 0..1
  const int wc   = wid & 1;     // wave col 0..1
  const int srow = lane >> 2;   // staging row within 16-row segment
  const int kch  = lane & 3;    // staging 16B chunk within row (4 x 8 fp16)
  const int fr   = lane & 15;
  const int fq   = lane >> 4;

  f32x4 acc[4][4] = {};

  for (int kt = 0; kt < K; kt += 32) {
#pragma unroll
    for (int c = 0; c < 2; ++c) {
      const int seg = c * 4 + wid;        // 0..7, wave-uniform
      const int r   = seg * 16 + srow;    // 0..127
      async_copy16(A  + (size_t)(brow + r) * K + kt + kch * 8, (char*)As + seg * 1024);
      async_copy16(Bw + (size_t)(bcol + r) * K + kt + kch * 8, (char*)Bs + seg * 1024);
    }
    __syncthreads();

    f16x8 af[4], bf[4];
#pragma unroll
    for (int m = 0; m < 4; ++m)
      af[m] = *(const f16x8*)&As[(wr * 64 + m * 16 + fr) * 32 + fq * 8];
#pragma unroll
    for (int n = 0; n < 4; ++n)
      bf[n] = *(const f16x8*)&Bs[(wc * 64 + n * 16 + fr) * 32 + fq * 8];
#pragma unroll
    for (int m = 0; m < 4; ++m)
#pragma unroll
      for (int n = 0; n < 4; ++n)
        acc[m][n] = __builtin_amdgcn_mfma_f32_16x16x32_f16(af[m], bf[n], acc[m][n], 0, 0, 0);
    __syncthreads();
  }

  if (MODE == 0) {
    _Float16* Co = (_Float16*)outp;
#pragma unroll
    for (int m = 0; m < 4; ++m) {
#pragma unroll
      for (int n = 0; n < 4; ++n) {
        const int col = bcol + wc * 64 + n * 16 + fr;
        const float bv = bias[col];
#pragma unroll
        for (int jj = 0; jj < 4; ++jj) {
          const int row = brow + wr * 64 + m * 16 + fq * 4 + jj;
          Co[(size_t)row * N + col] = (_Float16)(acc[m][n][jj] + bv);
        }
      }
    }
  } else {
    float* Co = (float*)outp;
#pragma unroll
    for (int m = 0; m < 4; ++m) {
#pragma unroll
      for (int n = 0; n < 4; ++n) {
        const int col = bcol + wc * 64 + n * 16 + fr;
        const float bv = bias[col];
#pragma unroll
        for (int jj = 0; jj < 4; ++jj) {
          const int row = brow + wr * 64 + m * 16 + fq * 4 + jj;
          const float u  = tanhf(acc[m][n][jj] + bv);
          const float z0 = (float)G[(size_t)row * FIVE_D + 2 * DIM + col];
          const float z1 = (float)G[(size_t)row * FIVE_D + 3 * DIM + col];
          const float xv = X[(size_t)row * DIM + col];
          const float hv = H[(size_t)row * DIM + col];
          Co[(size_t)row * DIM + col] = xv * z0 + hv * z1 + u * (1.0f - z0 - z1);
        }
      }
    }
  }
}

// ---------------------------------------------------------------------------
// launch
// ---------------------------------------------------------------------------
extern "C" void kernel_launch(void* const* d_in, const int* in_sizes, int n_in,
                              void* d_out, int out_size, void* d_ws, size_t ws_size,
                              hipStream_t stream)
{
  const float* x    = (const float*)d_in[0];
  const float* h    = (const float*)d_in[1];
  const float* Wg   = (const float*)d_in[2];
  const float* bg   = (const float*)d_in[3];
  const float* Wu   = (const float*)d_in[4];
  const float* bu   = (const float*)d_in[5];
  const float* lnw  = (const float*)d_in[6];
  const float* lnb  = (const float*)d_in[7];
  const float* ln2w = (const float*)d_in[8];
  const float* ln2b = (const float*)d_in[9];
  const float* mask = (const float*)d_in[10];

  // ws layout (bytes):
  //   [0,            5242880)   Wg fp16  [2560*1024]
  //   [5242880,      6291456)   Wu fp16  [512*1024]
  //   [6291456,     73400320)   inp fp16 [32768*1024]   (reused as inp2)
  //   [73400320,   241172480)   gates fp16 [32768*2560] (z0/z1 written in place)
  char* ws = (char*)d_ws;
  _Float16* wg16  = (_Float16*)(ws);
  _Float16* wu16  = (_Float16*)(ws + 5242880);
  _Float16* inp16 = (_Float16*)(ws + 6291456);
  _Float16* gates = (_Float16*)(ws + 73400320);

  cvt_kernel<<<2560, 256, 0, stream>>>(Wg, wg16, FIVE_D * TWO_D / 4);
  cvt_kernel<<<512, 256, 0, stream>>>(Wu, wu16, DIM * TWO_D / 4);

  ln1_kernel<<<BATCH, 256, 0, stream>>>(x, h, lnw, lnb, mask, inp16);

  gemm_f16<0><<<dim3(FIVE_D / 128, BATCH / 128), 256, 0, stream>>>(
      inp16, wg16, bg, (void*)gates, nullptr, nullptr, nullptr,
      BATCH, FIVE_D, TWO_D, FIVE_D / 128, (FIVE_D / 128) * (BATCH / 128));

  gate_ln2_kernel<<<BATCH, 128, 0, stream>>>(x, h, gates, ln2w, ln2b, mask, inp16);

  gemm_f16<1><<<dim3(DIM / 128, BATCH / 128), 256, 0, stream>>>(
      inp16, wu16, bu, d_out, x, h, gates,
      BATCH, DIM, TWO_D, DIM / 128, (DIM / 128) * (BATCH / 128));
}